// Round 1
// baseline (3136.784 us; speedup 1.0000x reference)
//
#include <hip/hip_runtime.h>

#define Nn 50000
#define Ee 800000

// ---------------------------------------------------------------------------
// Kernel 1: one lane per edge. Weights read through the scalar pipe
// (wave-uniform addresses -> s_load + v_fmac with SGPR operand). Per-lane
// activations live in one reusable LDS column buf[k][tid] (thread-private,
// no barriers). 64 accumulators per lane in VGPRs (j unrolled, k dynamic).
// ---------------------------------------------------------------------------
__global__ __launch_bounds__(256) void edge_kernel(
    const float* __restrict__ z, const float* __restrict__ cent,
    const int* __restrict__ ei,
    const float* __restrict__ We1, const float* __restrict__ be1,
    const float* __restrict__ We2, const float* __restrict__ be2,
    const float* __restrict__ Wm1, const float* __restrict__ bm1,
    const float* __restrict__ Wm2, const float* __restrict__ bm2,
    float* __restrict__ sums, float* __restrict__ cnt)
{
    __shared__ float buf[64][256];   // 64 KB: [k][tid], lanes consecutive -> conflict-free
    const int tid = threadIdx.x;
    const int e = blockIdx.x * 256 + tid;   // grid sized exactly: Ee/256

    const int src = ei[e];
    const int dst = ei[Ee + e];

    const float d0 = cent[dst * 3 + 0] - cent[src * 3 + 0];
    const float d1 = cent[dst * 3 + 1] - cent[src * 3 + 1];
    const float d2 = cent[dst * 3 + 2] - cent[src * 3 + 2];

    // ---- phi_e layer 1: e1 = relu(delta @ We1 + be1) -> LDS ----
    for (int j = 0; j < 64; ++j) {
        float v = fmaf(d0, We1[j], fmaf(d1, We1[64 + j], fmaf(d2, We1[128 + j], be1[j])));
        buf[j][tid] = fmaxf(v, 0.0f);
    }

    float acc[64];

    // ---- phi_e layer 2: e2 = relu(e1 @ We2 + be2) ----
    #pragma unroll
    for (int j = 0; j < 64; ++j) acc[j] = be2[j];
    for (int k = 0; k < 64; ++k) {
        const float ek = buf[k][tid];
        const float* __restrict__ wrow = We2 + k * 64;
        #pragma unroll
        for (int j = 0; j < 64; ++j) acc[j] = fmaf(ek, wrow[j], acc[j]);
    }
    #pragma unroll
    for (int j = 0; j < 64; ++j) buf[j][tid] = fmaxf(acc[j], 0.0f);   // e2 replaces e1

    // ---- phi_m layer 1: h1 = relu([z_src, z_dst, e2] @ Wm1 + bm1) ----
    #pragma unroll
    for (int j = 0; j < 64; ++j) acc[j] = bm1[j];
    const float* __restrict__ zs = z + src * 64;
    for (int k = 0; k < 64; ++k) {
        const float hk = zs[k];                       // gather, L2/L3-resident
        const float* __restrict__ wrow = Wm1 + k * 64;
        #pragma unroll
        for (int j = 0; j < 64; ++j) acc[j] = fmaf(hk, wrow[j], acc[j]);
    }
    const float* __restrict__ zd = z + dst * 64;
    for (int k = 0; k < 64; ++k) {
        const float hk = zd[k];
        const float* __restrict__ wrow = Wm1 + (64 + k) * 64;
        #pragma unroll
        for (int j = 0; j < 64; ++j) acc[j] = fmaf(hk, wrow[j], acc[j]);
    }
    for (int k = 0; k < 64; ++k) {
        const float hk = buf[k][tid];
        const float* __restrict__ wrow = Wm1 + (128 + k) * 64;
        #pragma unroll
        for (int j = 0; j < 64; ++j) acc[j] = fmaf(hk, wrow[j], acc[j]);
    }
    #pragma unroll
    for (int j = 0; j < 64; ++j) buf[j][tid] = fmaxf(acc[j], 0.0f);   // h1 replaces e2

    // ---- phi_m layer 2: m = h1 @ Wm2 + bm2  (no relu) ----
    #pragma unroll
    for (int j = 0; j < 64; ++j) acc[j] = bm2[j];
    for (int k = 0; k < 64; ++k) {
        const float hk = buf[k][tid];
        const float* __restrict__ wrow = Wm2 + k * 64;
        #pragma unroll
        for (int j = 0; j < 64; ++j) acc[j] = fmaf(hk, wrow[j], acc[j]);
    }

    // ---- scatter: sums[dst] += m ; cnt[dst] += 1 ----
    float* __restrict__ srow = sums + dst * 64;
    #pragma unroll
    for (int j = 0; j < 64; ++j) atomicAdd(&srow[j], acc[j]);
    atomicAdd(&cnt[dst], 1.0f);
}

// ---------------------------------------------------------------------------
// Kernel 2: one wave per node, lane = output feature. Reads sums in-place
// from d_out, divides by count, applies phi_u, overwrites d_out.
// Activation broadcast across lanes via __shfl (wave-uniform row).
// ---------------------------------------------------------------------------
__global__ __launch_bounds__(256) void node_kernel(
    const float* __restrict__ z,
    const float* __restrict__ Wu1, const float* __restrict__ bu1,
    float* __restrict__ out, const float* __restrict__ cnt)
{
    const int node = (blockIdx.x * 256 + threadIdx.x) >> 6;   // grid sized exactly
    const int j = threadIdx.x & 63;
    const int base = node * 64;

    const float inv = 1.0f / fmaxf(cnt[node], 1.0f);
    const float zj = z[base + j];
    const float mj = out[base + j] * inv;   // M[node][j]

    float a = bu1[j];
    for (int k = 0; k < 64; ++k)
        a = fmaf(__shfl(zj, k, 64), Wu1[k * 64 + j], a);
    for (int k = 0; k < 64; ++k)
        a = fmaf(__shfl(mj, k, 64), Wu1[(64 + k) * 64 + j], a);

    out[base + j] = fmaxf(a, 0.0f);   // all reads of this row happened above
}

extern "C" void kernel_launch(void* const* d_in, const int* in_sizes, int n_in,
                              void* d_out, int out_size, void* d_ws, size_t ws_size,
                              hipStream_t stream) {
    const float* z    = (const float*)d_in[0];
    const float* cent = (const float*)d_in[1];
    const int*   ei   = (const int*)d_in[2];
    const float* We1  = (const float*)d_in[3];
    const float* be1  = (const float*)d_in[4];
    const float* We2  = (const float*)d_in[5];
    const float* be2  = (const float*)d_in[6];
    const float* Wm1  = (const float*)d_in[7];
    const float* bm1  = (const float*)d_in[8];
    const float* Wm2  = (const float*)d_in[9];
    const float* bm2  = (const float*)d_in[10];
    const float* Wu1  = (const float*)d_in[11];
    const float* bu1  = (const float*)d_in[12];

    float* out = (float*)d_out;          // reused as the scatter-sum buffer [N,64]
    float* cnt = (float*)d_ws;           // [N] float counts

    hipMemsetAsync(out, 0, (size_t)Nn * 64 * sizeof(float), stream);
    hipMemsetAsync(cnt, 0, (size_t)Nn * sizeof(float), stream);

    edge_kernel<<<Ee / 256, 256, 0, stream>>>(z, cent, ei,
        We1, be1, We2, be2, Wm1, bm1, Wm2, bm2, out, cnt);
    node_kernel<<<Nn / 4, 256, 0, stream>>>(z, Wu1, bu1, out, cnt);
}

// Round 2
// 1101.752 us; speedup vs baseline: 2.8471x; 2.8471x over previous
//
#include <hip/hip_runtime.h>

#define Nn 50000
#define Ee 800000

// ---- workspace layout (CSR path) ----
#define MBUF_BYTES  ((size_t)Ee * 64 * 4)            // 204,800,000
#define ORDER_OFF   MBUF_BYTES
#define ORDER_BYTES ((size_t)Ee * 4)                 // 3,200,000
#define DEG_OFF     (ORDER_OFF + ORDER_BYTES)        // 208,000,000
#define DEG_BYTES   ((size_t)Nn * 4)
#define OFF_OFF     (DEG_OFF + DEG_BYTES)            // 208,200,000
#define TOTAL_WS    (OFF_OFF + (size_t)Nn * 4)       // 208,400,000

// ===========================================================================
// CSR-build kernels
// ===========================================================================
__global__ __launch_bounds__(256) void hist_kernel(const int* __restrict__ ei,
                                                   int* __restrict__ deg) {
    const int e = blockIdx.x * 256 + threadIdx.x;
    atomicAdd(&deg[ei[Ee + e]], 1);
}

// single-block exclusive scan of deg[Nn] -> off[Nn]
__global__ __launch_bounds__(1024) void scan_kernel(const int* __restrict__ deg,
                                                    int* __restrict__ off) {
    __shared__ int s[1024];
    __shared__ int carry;
    const int tid = threadIdx.x;
    if (tid == 0) carry = 0;
    __syncthreads();
    for (int base = 0; base < Nn; base += 1024) {
        const int i = base + tid;
        const int v = (i < Nn) ? deg[i] : 0;
        s[tid] = v;
        __syncthreads();
        for (int st = 1; st < 1024; st <<= 1) {
            int t = (tid >= st) ? s[tid - st] : 0;
            __syncthreads();
            s[tid] += t;
            __syncthreads();
        }
        const int incl = s[tid];
        if (i < Nn) off[i] = carry + incl - v;   // exclusive
        __syncthreads();
        if (tid == 1023) carry += incl;          // chunk total
        __syncthreads();
    }
}

// off[dst] is destroyed (becomes end pointer); start recovered via deg.
__global__ __launch_bounds__(256) void fill_kernel(const int* __restrict__ ei,
                                                   int* __restrict__ off,
                                                   int* __restrict__ order) {
    const int e = blockIdx.x * 256 + threadIdx.x;
    const int pos = atomicAdd(&off[ei[Ee + e]], 1);
    order[pos] = e;
}

// ===========================================================================
// Edge kernel (CSR): lane = sorted slot p, edge = order[p]. Weights via
// wave-uniform (scalar) loads; activations in a thread-private LDS column;
// m written with plain float4 stores to m_buf[p*64..] — no atomics.
// ===========================================================================
__global__ __launch_bounds__(128) void edge_kernel_csr(
    const float* __restrict__ z, const float* __restrict__ cent,
    const int* __restrict__ ei, const int* __restrict__ order,
    const float* __restrict__ We1, const float* __restrict__ be1,
    const float* __restrict__ We2, const float* __restrict__ be2,
    const float* __restrict__ Wm1, const float* __restrict__ bm1,
    const float* __restrict__ Wm2, const float* __restrict__ bm2,
    float* __restrict__ m_buf)
{
    __shared__ float buf[64][128];   // 32 KB -> 5 blocks/CU
    const int tid = threadIdx.x;
    const int p = blockIdx.x * 128 + tid;   // grid exact: Ee/128
    const int e = order[p];

    const int src = ei[e];
    const int dst = ei[Ee + e];

    const float d0 = cent[dst * 3 + 0] - cent[src * 3 + 0];
    const float d1 = cent[dst * 3 + 1] - cent[src * 3 + 1];
    const float d2 = cent[dst * 3 + 2] - cent[src * 3 + 2];

    // ---- phi_e layer 1 ----
    for (int j = 0; j < 64; ++j) {
        float v = fmaf(d0, We1[j], fmaf(d1, We1[64 + j], fmaf(d2, We1[128 + j], be1[j])));
        buf[j][tid] = fmaxf(v, 0.0f);
    }

    float acc[64];

    // ---- phi_e layer 2 ----
    #pragma unroll
    for (int j = 0; j < 64; ++j) acc[j] = be2[j];
    for (int k = 0; k < 64; ++k) {
        const float ek = buf[k][tid];
        const float* __restrict__ wrow = We2 + k * 64;
        #pragma unroll
        for (int j = 0; j < 64; ++j) acc[j] = fmaf(ek, wrow[j], acc[j]);
    }
    #pragma unroll
    for (int j = 0; j < 64; ++j) buf[j][tid] = fmaxf(acc[j], 0.0f);

    // ---- phi_m layer 1: [z_src, z_dst, e2] @ Wm1 ----
    #pragma unroll
    for (int j = 0; j < 64; ++j) acc[j] = bm1[j];
    const float* __restrict__ zs = z + src * 64;
    for (int k = 0; k < 64; ++k) {
        const float hk = zs[k];
        const float* __restrict__ wrow = Wm1 + k * 64;
        #pragma unroll
        for (int j = 0; j < 64; ++j) acc[j] = fmaf(hk, wrow[j], acc[j]);
    }
    const float* __restrict__ zd = z + dst * 64;
    for (int k = 0; k < 64; ++k) {
        const float hk = zd[k];
        const float* __restrict__ wrow = Wm1 + (64 + k) * 64;
        #pragma unroll
        for (int j = 0; j < 64; ++j) acc[j] = fmaf(hk, wrow[j], acc[j]);
    }
    for (int k = 0; k < 64; ++k) {
        const float hk = buf[k][tid];
        const float* __restrict__ wrow = Wm1 + (128 + k) * 64;
        #pragma unroll
        for (int j = 0; j < 64; ++j) acc[j] = fmaf(hk, wrow[j], acc[j]);
    }
    #pragma unroll
    for (int j = 0; j < 64; ++j) buf[j][tid] = fmaxf(acc[j], 0.0f);

    // ---- phi_m layer 2 (no relu) ----
    #pragma unroll
    for (int j = 0; j < 64; ++j) acc[j] = bm2[j];
    for (int k = 0; k < 64; ++k) {
        const float hk = buf[k][tid];
        const float* __restrict__ wrow = Wm2 + k * 64;
        #pragma unroll
        for (int j = 0; j < 64; ++j) acc[j] = fmaf(hk, wrow[j], acc[j]);
    }

    // ---- store m at sorted slot p (float4, block region contiguous) ----
    float* __restrict__ mrow = m_buf + (size_t)p * 64;
    #pragma unroll
    for (int j4 = 0; j4 < 16; ++j4) {
        float4 v = make_float4(acc[4 * j4], acc[4 * j4 + 1], acc[4 * j4 + 2], acc[4 * j4 + 3]);
        *(float4*)(mrow + 4 * j4) = v;
    }
}

// ===========================================================================
// Node kernel (CSR): wave per node, lane = feature. Sequential read of the
// node's contiguous m_buf range, then phi_u via shfl broadcast.
// ===========================================================================
__global__ __launch_bounds__(256) void node_kernel_csr(
    const float* __restrict__ z,
    const float* __restrict__ Wu1, const float* __restrict__ bu1,
    const float* __restrict__ m_buf, const int* __restrict__ deg,
    const int* __restrict__ off, float* __restrict__ out)
{
    const int node = (blockIdx.x * 256 + threadIdx.x) >> 6;   // grid exact: Nn/4
    const int j = threadIdx.x & 63;
    const int dn = deg[node];
    const int start = off[node] - dn;   // off was advanced to end by fill

    float s = 0.0f;
    const float* __restrict__ mp = m_buf + (size_t)start * 64 + j;
    for (int i = 0; i < dn; ++i) s += mp[(size_t)i * 64];
    const float M = s * (1.0f / fmaxf((float)dn, 1.0f));

    const float zj = z[node * 64 + j];
    float a = bu1[j];
    for (int k = 0; k < 64; ++k)
        a = fmaf(__shfl(zj, k, 64), Wu1[k * 64 + j], a);
    for (int k = 0; k < 64; ++k)
        a = fmaf(__shfl(M, k, 64), Wu1[(64 + k) * 64 + j], a);

    out[node * 64 + j] = fmaxf(a, 0.0f);
}

// ===========================================================================
// Fallback path (round-1 atomic version) — used only if ws_size is too small.
// ===========================================================================
__global__ __launch_bounds__(256) void edge_kernel_atomic(
    const float* __restrict__ z, const float* __restrict__ cent,
    const int* __restrict__ ei,
    const float* __restrict__ We1, const float* __restrict__ be1,
    const float* __restrict__ We2, const float* __restrict__ be2,
    const float* __restrict__ Wm1, const float* __restrict__ bm1,
    const float* __restrict__ Wm2, const float* __restrict__ bm2,
    float* __restrict__ sums, float* __restrict__ cnt)
{
    __shared__ float buf[64][256];
    const int tid = threadIdx.x;
    const int e = blockIdx.x * 256 + tid;
    const int src = ei[e];
    const int dst = ei[Ee + e];
    const float d0 = cent[dst * 3 + 0] - cent[src * 3 + 0];
    const float d1 = cent[dst * 3 + 1] - cent[src * 3 + 1];
    const float d2 = cent[dst * 3 + 2] - cent[src * 3 + 2];
    for (int j = 0; j < 64; ++j) {
        float v = fmaf(d0, We1[j], fmaf(d1, We1[64 + j], fmaf(d2, We1[128 + j], be1[j])));
        buf[j][tid] = fmaxf(v, 0.0f);
    }
    float acc[64];
    #pragma unroll
    for (int j = 0; j < 64; ++j) acc[j] = be2[j];
    for (int k = 0; k < 64; ++k) {
        const float ek = buf[k][tid];
        const float* __restrict__ wrow = We2 + k * 64;
        #pragma unroll
        for (int j = 0; j < 64; ++j) acc[j] = fmaf(ek, wrow[j], acc[j]);
    }
    #pragma unroll
    for (int j = 0; j < 64; ++j) buf[j][tid] = fmaxf(acc[j], 0.0f);
    #pragma unroll
    for (int j = 0; j < 64; ++j) acc[j] = bm1[j];
    const float* __restrict__ zs = z + src * 64;
    for (int k = 0; k < 64; ++k) {
        const float hk = zs[k];
        const float* __restrict__ wrow = Wm1 + k * 64;
        #pragma unroll
        for (int j = 0; j < 64; ++j) acc[j] = fmaf(hk, wrow[j], acc[j]);
    }
    const float* __restrict__ zd = z + dst * 64;
    for (int k = 0; k < 64; ++k) {
        const float hk = zd[k];
        const float* __restrict__ wrow = Wm1 + (64 + k) * 64;
        #pragma unroll
        for (int j = 0; j < 64; ++j) acc[j] = fmaf(hk, wrow[j], acc[j]);
    }
    for (int k = 0; k < 64; ++k) {
        const float hk = buf[k][tid];
        const float* __restrict__ wrow = Wm1 + (128 + k) * 64;
        #pragma unroll
        for (int j = 0; j < 64; ++j) acc[j] = fmaf(hk, wrow[j], acc[j]);
    }
    #pragma unroll
    for (int j = 0; j < 64; ++j) buf[j][tid] = fmaxf(acc[j], 0.0f);
    #pragma unroll
    for (int j = 0; j < 64; ++j) acc[j] = bm2[j];
    for (int k = 0; k < 64; ++k) {
        const float hk = buf[k][tid];
        const float* __restrict__ wrow = Wm2 + k * 64;
        #pragma unroll
        for (int j = 0; j < 64; ++j) acc[j] = fmaf(hk, wrow[j], acc[j]);
    }
    float* __restrict__ srow = sums + dst * 64;
    #pragma unroll
    for (int j = 0; j < 64; ++j) atomicAdd(&srow[j], acc[j]);
    atomicAdd(&cnt[dst], 1.0f);
}

__global__ __launch_bounds__(256) void node_kernel_atomic(
    const float* __restrict__ z,
    const float* __restrict__ Wu1, const float* __restrict__ bu1,
    float* __restrict__ out, const float* __restrict__ cnt)
{
    const int node = (blockIdx.x * 256 + threadIdx.x) >> 6;
    const int j = threadIdx.x & 63;
    const int base = node * 64;
    const float inv = 1.0f / fmaxf(cnt[node], 1.0f);
    const float zj = z[base + j];
    const float mj = out[base + j] * inv;
    float a = bu1[j];
    for (int k = 0; k < 64; ++k)
        a = fmaf(__shfl(zj, k, 64), Wu1[k * 64 + j], a);
    for (int k = 0; k < 64; ++k)
        a = fmaf(__shfl(mj, k, 64), Wu1[(64 + k) * 64 + j], a);
    out[base + j] = fmaxf(a, 0.0f);
}

extern "C" void kernel_launch(void* const* d_in, const int* in_sizes, int n_in,
                              void* d_out, int out_size, void* d_ws, size_t ws_size,
                              hipStream_t stream) {
    const float* z    = (const float*)d_in[0];
    const float* cent = (const float*)d_in[1];
    const int*   ei   = (const int*)d_in[2];
    const float* We1  = (const float*)d_in[3];
    const float* be1  = (const float*)d_in[4];
    const float* We2  = (const float*)d_in[5];
    const float* be2  = (const float*)d_in[6];
    const float* Wm1  = (const float*)d_in[7];
    const float* bm1  = (const float*)d_in[8];
    const float* Wm2  = (const float*)d_in[9];
    const float* bm2  = (const float*)d_in[10];
    const float* Wu1  = (const float*)d_in[11];
    const float* bu1  = (const float*)d_in[12];
    float* out = (float*)d_out;

    if (ws_size >= TOTAL_WS) {
        float* m_buf = (float*)d_ws;
        int* order   = (int*)((char*)d_ws + ORDER_OFF);
        int* deg     = (int*)((char*)d_ws + DEG_OFF);
        int* off     = (int*)((char*)d_ws + OFF_OFF);

        hipMemsetAsync(deg, 0, Nn * sizeof(int), stream);
        hist_kernel<<<Ee / 256, 256, 0, stream>>>(ei, deg);
        scan_kernel<<<1, 1024, 0, stream>>>(deg, off);
        fill_kernel<<<Ee / 256, 256, 0, stream>>>(ei, off, order);
        edge_kernel_csr<<<Ee / 128, 128, 0, stream>>>(z, cent, ei, order,
            We1, be1, We2, be2, Wm1, bm1, Wm2, bm2, m_buf);
        node_kernel_csr<<<Nn / 4, 256, 0, stream>>>(z, Wu1, bu1, m_buf, deg, off, out);
    } else {
        float* cnt = (float*)d_ws;
        hipMemsetAsync(out, 0, (size_t)Nn * 64 * sizeof(float), stream);
        hipMemsetAsync(cnt, 0, (size_t)Nn * sizeof(float), stream);
        edge_kernel_atomic<<<Ee / 256, 256, 0, stream>>>(z, cent, ei,
            We1, be1, We2, be2, Wm1, bm1, Wm2, bm2, out, cnt);
        node_kernel_atomic<<<Nn / 4, 256, 0, stream>>>(z, Wu1, bu1, out, cnt);
    }
}

// Round 3
// 428.104 us; speedup vs baseline: 7.3272x; 2.5736x over previous
//
#include <hip/hip_runtime.h>

#define Nn 50000
#define Ee 800000

typedef _Float16 half8 __attribute__((ext_vector_type(8)));
typedef float floatx16 __attribute__((ext_vector_type(16)));

// ---- workspace layout ----
#define MBUF_HALVES ((size_t)Ee * 64)                    // f16 m_buf
#define MBUF_BYTES  (MBUF_HALVES * 2)                    // 102,400,000
#define ORDER_OFF   MBUF_BYTES
#define ORDER_BYTES ((size_t)Ee * 4)
#define DEG_OFF     (ORDER_OFF + ORDER_BYTES)
#define OFF_OFF     (DEG_OFF + (size_t)Nn * 4)
#define BSUM_OFF    (OFF_OFF + (size_t)Nn * 4)
#define WT_OFF      (BSUM_OFF + 256)                     // 16B-aligned
#define WT_HALVES   21504                                // 1024+4096+12288+4096
#define TOTAL_WS    (WT_OFF + (size_t)WT_HALVES * 2)

// wt sub-offsets (in halves)
#define WE1T 0
#define WE2T 1024
#define WM1T 5120
#define WM2T 17408

// ===========================================================================
// CSR build
// ===========================================================================
__global__ __launch_bounds__(256) void hist_kernel(const int* __restrict__ ei,
                                                   int* __restrict__ deg) {
    const int e = blockIdx.x * 256 + threadIdx.x;
    atomicAdd(&deg[ei[Ee + e]], 1);
}

#define SCAN_TILE 4096
#define SCAN_NBLK 13   // ceil(50000/4096)

__global__ __launch_bounds__(1024) void scan1_kernel(const int* __restrict__ deg,
                                                     int* __restrict__ off,
                                                     int* __restrict__ bsum) {
    __shared__ int wsum[16];
    const int tid = threadIdx.x;
    const int lane = tid & 63, wid = tid >> 6;
    const int base = blockIdx.x * SCAN_TILE + tid * 4;

    int v0 = (base + 0 < Nn) ? deg[base + 0] : 0;
    int v1 = (base + 1 < Nn) ? deg[base + 1] : 0;
    int v2 = (base + 2 < Nn) ? deg[base + 2] : 0;
    int v3 = (base + 3 < Nn) ? deg[base + 3] : 0;
    const int tsum = v0 + v1 + v2 + v3;

    int x = tsum;                                  // wave inclusive scan
    for (int s = 1; s < 64; s <<= 1) {
        int y = __shfl_up(x, s, 64);
        if (lane >= s) x += y;
    }
    if (lane == 63) wsum[wid] = x;
    __syncthreads();
    if (wid == 0) {
        int w = (lane < 16) ? wsum[lane] : 0;
        for (int s = 1; s < 16; s <<= 1) {
            int y = __shfl_up(w, s, 64);
            if (lane >= s) w += y;
        }
        if (lane < 16) wsum[lane] = w;             // inclusive wave sums
    }
    __syncthreads();
    const int wpre = wid ? wsum[wid - 1] : 0;
    const int tpre = wpre + (x - tsum);            // exclusive thread prefix
    if (base + 0 < Nn) off[base + 0] = tpre;
    if (base + 1 < Nn) off[base + 1] = tpre + v0;
    if (base + 2 < Nn) off[base + 2] = tpre + v0 + v1;
    if (base + 3 < Nn) off[base + 3] = tpre + v0 + v1 + v2;
    if (tid == 0) bsum[blockIdx.x] = 0;            // placeholder, fixed below
    if (tid == 1023) bsum[blockIdx.x] = wsum[15];
}

__global__ __launch_bounds__(64) void scan2_kernel(int* __restrict__ bsum) {
    const int lane = threadIdx.x;
    int v = (lane < SCAN_NBLK) ? bsum[lane] : 0;
    int w = v;
    for (int s = 1; s < 64; s <<= 1) {
        int y = __shfl_up(w, s, 64);
        if (lane >= s) w += y;
    }
    if (lane < SCAN_NBLK) bsum[lane] = w - v;      // exclusive
}

__global__ __launch_bounds__(1024) void scan3_kernel(int* __restrict__ off,
                                                     const int* __restrict__ bsum) {
    const int add = bsum[blockIdx.x];
    const int base = blockIdx.x * SCAN_TILE + threadIdx.x * 4;
    if (base + 0 < Nn) off[base + 0] += add;
    if (base + 1 < Nn) off[base + 1] += add;
    if (base + 2 < Nn) off[base + 2] += add;
    if (base + 3 < Nn) off[base + 3] += add;
}

// off[dst] advanced to end pointer; start recovered via deg.
__global__ __launch_bounds__(256) void fill_kernel(const int* __restrict__ ei,
                                                   int* __restrict__ off,
                                                   int* __restrict__ order) {
    const int e = blockIdx.x * 256 + threadIdx.x;
    const int pos = atomicAdd(&off[ei[Ee + e]], 1);
    order[pos] = e;
}

// ===========================================================================
// Weight prep: transpose + fp32->f16.  wt[n][k] = W[k][n].
// ===========================================================================
__global__ __launch_bounds__(256) void wprep_kernel(
    const float* __restrict__ We1, const float* __restrict__ We2,
    const float* __restrict__ Wm1, const float* __restrict__ Wm2,
    _Float16* __restrict__ wt) {
    const int i = blockIdx.x * 256 + threadIdx.x;   // grid exact: 21504/256=84
    float v;
    if (i < 1024) {                      // We1t [64][16], K=3 zero-padded
        const int n = i >> 4, k = i & 15;
        v = (k < 3) ? We1[k * 64 + n] : 0.0f;
    } else if (i < 5120) {               // We2t [64][64]
        const int j = i - 1024, n = j >> 6, k = j & 63;
        v = We2[k * 64 + n];
    } else if (i < 17408) {              // Wm1t [64][192]
        const int j = i - 5120, n = j / 192, k = j - n * 192;
        v = Wm1[k * 64 + n];
    } else {                             // Wm2t [64][64]
        const int j = i - 17408, n = j >> 6, k = j & 63;
        v = Wm2[k * 64 + n];
    }
    wt[i] = (_Float16)v;
}

// ===========================================================================
// Edge kernel (MFMA f16): wave = 32 edges, no barriers, per-wave LDS h-buffer.
// A-frag (32x32x16): A[m=lane&31][k=(lane>>5)*8+j]
// B-frag:            B[k=(lane>>5)*8+j][n=lane&31]  (read from wt[n][k] rows)
// C/D:               row=(reg&3)+8*(reg>>2)+4*(lane>>5), col=lane&31
// ===========================================================================
#define HPITCH 200

__device__ __forceinline__ floatx16 mfma16(half8 a, half8 b, floatx16 c) {
    return __builtin_amdgcn_mfma_f32_32x32x16_f16(a, b, c, 0, 0, 0);
}

__global__ __launch_bounds__(256) void edge_mfma_kernel(
    const float* __restrict__ z, const float* __restrict__ cent,
    const int* __restrict__ ei, const int* __restrict__ order,
    const _Float16* __restrict__ wt,
    const float* __restrict__ be1, const float* __restrict__ be2,
    const float* __restrict__ bm1, const float* __restrict__ bm2,
    _Float16* __restrict__ m_buf)
{
    __shared__ _Float16 hb[4][32][HPITCH];   // 51.2 KB -> 3 blocks/CU
    const int tid = threadIdx.x;
    const int wid = tid >> 6, lane = tid & 63;
    const int er = lane & 31;        // edge row within the wave tile
    const int kh = lane >> 5;        // k-half selector (0: k 0-7, 1: k 8-15)
    const int tile = (blockIdx.x * 4 + wid) * 32;

    // ---- indices (lanes l and l+32 handle edge er: l<32->src row, else dst)
    const int p = tile + er;
    const int e = order[p];
    const int src = ei[e], dst = ei[Ee + e];
    const int row = kh ? dst : src;

    // ---- z gather: each lane converts one 64-float row -> f16 -> LDS ----
    const float* __restrict__ zr = z + (size_t)row * 64;
    _Float16* __restrict__ hrow = &hb[wid][er][kh * 64];
    #pragma unroll
    for (int c = 0; c < 8; ++c) {
        const float4 a4 = *(const float4*)(zr + c * 8);
        const float4 b4 = *(const float4*)(zr + c * 8 + 4);
        half8 hv;
        hv[0] = (_Float16)a4.x; hv[1] = (_Float16)a4.y;
        hv[2] = (_Float16)a4.z; hv[3] = (_Float16)a4.w;
        hv[4] = (_Float16)b4.x; hv[5] = (_Float16)b4.y;
        hv[6] = (_Float16)b4.z; hv[7] = (_Float16)b4.w;
        *(half8*)(hrow + c * 8) = hv;
    }

    // ---- centroid delta for edge er (src vals live in lane er, dst in er+32)
    const float c0 = cent[row * 3 + 0];
    const float c1 = cent[row * 3 + 1];
    const float c2 = cent[row * 3 + 2];
    const float d0 = __shfl(c0, er + 32, 64) - __shfl(c0, er, 64);
    const float d1 = __shfl(c1, er + 32, 64) - __shfl(c1, er, 64);
    const float d2 = __shfl(c2, er + 32, 64) - __shfl(c2, er, 64);

    const _Float16* __restrict__ we1t = wt + WE1T;
    const _Float16* __restrict__ we2t = wt + WE2T;
    const _Float16* __restrict__ wm1t = wt + WM1T;
    const _Float16* __restrict__ wm2t = wt + WM2T;

    // ---- e1 = relu(delta @ We1 + be1): K=16 (3 real), 2 n-tiles ----
    half8 a1;
    #pragma unroll
    for (int j = 0; j < 8; ++j) a1[j] = (_Float16)0.0f;
    if (kh == 0) { a1[0] = (_Float16)d0; a1[1] = (_Float16)d1; a1[2] = (_Float16)d2; }

    #pragma unroll
    for (int nt = 0; nt < 2; ++nt) {
        const int n = nt * 32 + er;
        const float bias = be1[n];
        floatx16 acc;
        #pragma unroll
        for (int r = 0; r < 16; ++r) acc[r] = bias;
        const half8 b = *(const half8*)(we1t + n * 16 + kh * 8);
        acc = mfma16(a1, b, acc);
        #pragma unroll
        for (int r = 0; r < 16; ++r) {
            const int rrow = (r & 3) + 8 * (r >> 2) + 4 * kh;
            hb[wid][rrow][128 + n] = (_Float16)fmaxf(acc[r], 0.0f);
        }
    }

    // ---- e2 = relu(e1 @ We2 + be2): K=64, A from h cols 128..191 ----
    {
        const float bias0 = be2[er], bias1 = be2[32 + er];
        floatx16 acc0, acc1;
        #pragma unroll
        for (int r = 0; r < 16; ++r) { acc0[r] = bias0; acc1[r] = bias1; }
        #pragma unroll
        for (int ks = 0; ks < 4; ++ks) {
            const half8 a = *(const half8*)(&hb[wid][er][128 + ks * 16 + kh * 8]);
            const half8 b0 = *(const half8*)(we2t + er * 64 + ks * 16 + kh * 8);
            const half8 b1 = *(const half8*)(we2t + (32 + er) * 64 + ks * 16 + kh * 8);
            acc0 = mfma16(a, b0, acc0);
            acc1 = mfma16(a, b1, acc1);
        }
        #pragma unroll
        for (int r = 0; r < 16; ++r) {   // overwrite e1 region (reads done)
            const int rrow = (r & 3) + 8 * (r >> 2) + 4 * kh;
            hb[wid][rrow][128 + er]      = (_Float16)fmaxf(acc0[r], 0.0f);
            hb[wid][rrow][128 + 32 + er] = (_Float16)fmaxf(acc1[r], 0.0f);
        }
    }

    // ---- h1 = relu([z_src|z_dst|e2] @ Wm1 + bm1): K=192 ----
    {
        const float bias0 = bm1[er], bias1 = bm1[32 + er];
        floatx16 acc0, acc1;
        #pragma unroll
        for (int r = 0; r < 16; ++r) { acc0[r] = bias0; acc1[r] = bias1; }
        #pragma unroll
        for (int ks = 0; ks < 12; ++ks) {
            const half8 a = *(const half8*)(&hb[wid][er][ks * 16 + kh * 8]);
            const half8 b0 = *(const half8*)(wm1t + er * 192 + ks * 16 + kh * 8);
            const half8 b1 = *(const half8*)(wm1t + (32 + er) * 192 + ks * 16 + kh * 8);
            acc0 = mfma16(a, b0, acc0);
            acc1 = mfma16(a, b1, acc1);
        }
        #pragma unroll
        for (int r = 0; r < 16; ++r) {   // h1 -> cols 0..63 (z_src dead now)
            const int rrow = (r & 3) + 8 * (r >> 2) + 4 * kh;
            hb[wid][rrow][er]      = (_Float16)fmaxf(acc0[r], 0.0f);
            hb[wid][rrow][32 + er] = (_Float16)fmaxf(acc1[r], 0.0f);
        }
    }

    // ---- m = h1 @ Wm2 + bm2 (no relu) -> m_buf f16 at sorted slots ----
    {
        const float bias0 = bm2[er], bias1 = bm2[32 + er];
        floatx16 acc0, acc1;
        #pragma unroll
        for (int r = 0; r < 16; ++r) { acc0[r] = bias0; acc1[r] = bias1; }
        #pragma unroll
        for (int ks = 0; ks < 4; ++ks) {
            const half8 a = *(const half8*)(&hb[wid][er][ks * 16 + kh * 8]);
            const half8 b0 = *(const half8*)(wm2t + er * 64 + ks * 16 + kh * 8);
            const half8 b1 = *(const half8*)(wm2t + (32 + er) * 64 + ks * 16 + kh * 8);
            acc0 = mfma16(a, b0, acc0);
            acc1 = mfma16(a, b1, acc1);
        }
        #pragma unroll
        for (int r = 0; r < 16; ++r) {
            const int rrow = (r & 3) + 8 * (r >> 2) + 4 * kh;
            _Float16* mrow = m_buf + (size_t)(tile + rrow) * 64;
            mrow[er]      = (_Float16)acc0[r];
            mrow[32 + er] = (_Float16)acc1[r];
        }
    }
}

// ===========================================================================
// Node kernel: wave per node, lane = feature. Sequential f16 m_buf reads,
// mean, then phi_u (fp32 VALU) via shfl broadcast.
// ===========================================================================
__global__ __launch_bounds__(256) void node_kernel(
    const float* __restrict__ z,
    const float* __restrict__ Wu1, const float* __restrict__ bu1,
    const _Float16* __restrict__ m_buf, const int* __restrict__ deg,
    const int* __restrict__ off, float* __restrict__ out)
{
    const int node = (blockIdx.x * 256 + threadIdx.x) >> 6;   // grid exact
    const int j = threadIdx.x & 63;
    const int dn = deg[node];
    const int start = off[node] - dn;   // off advanced to end by fill

    float s = 0.0f;
    const _Float16* __restrict__ mp = m_buf + (size_t)start * 64 + j;
    for (int i = 0; i < dn; ++i) s += (float)mp[(size_t)i * 64];
    const float M = s * (1.0f / fmaxf((float)dn, 1.0f));

    const float zj = z[node * 64 + j];
    float a = bu1[j];
    for (int k = 0; k < 64; ++k)
        a = fmaf(__shfl(zj, k, 64), Wu1[k * 64 + j], a);
    for (int k = 0; k < 64; ++k)
        a = fmaf(__shfl(M, k, 64), Wu1[(64 + k) * 64 + j], a);

    out[node * 64 + j] = fmaxf(a, 0.0f);
}

// ===========================================================================
// Fallback (atomic, fp32) — only if ws_size too small. Known-correct (R1).
// ===========================================================================
__global__ __launch_bounds__(256) void edge_kernel_atomic(
    const float* __restrict__ z, const float* __restrict__ cent,
    const int* __restrict__ ei,
    const float* __restrict__ We1, const float* __restrict__ be1,
    const float* __restrict__ We2, const float* __restrict__ be2,
    const float* __restrict__ Wm1, const float* __restrict__ bm1,
    const float* __restrict__ Wm2, const float* __restrict__ bm2,
    float* __restrict__ sums, float* __restrict__ cnt)
{
    __shared__ float buf[64][256];
    const int tid = threadIdx.x;
    const int e = blockIdx.x * 256 + tid;
    const int src = ei[e];
    const int dst = ei[Ee + e];
    const float d0 = cent[dst * 3 + 0] - cent[src * 3 + 0];
    const float d1 = cent[dst * 3 + 1] - cent[src * 3 + 1];
    const float d2 = cent[dst * 3 + 2] - cent[src * 3 + 2];
    for (int j = 0; j < 64; ++j) {
        float v = fmaf(d0, We1[j], fmaf(d1, We1[64 + j], fmaf(d2, We1[128 + j], be1[j])));
        buf[j][tid] = fmaxf(v, 0.0f);
    }
    float acc[64];
    #pragma unroll
    for (int j = 0; j < 64; ++j) acc[j] = be2[j];
    for (int k = 0; k < 64; ++k) {
        const float ek = buf[k][tid];
        const float* wrow = We2 + k * 64;
        #pragma unroll
        for (int j = 0; j < 64; ++j) acc[j] = fmaf(ek, wrow[j], acc[j]);
    }
    #pragma unroll
    for (int j = 0; j < 64; ++j) buf[j][tid] = fmaxf(acc[j], 0.0f);
    #pragma unroll
    for (int j = 0; j < 64; ++j) acc[j] = bm1[j];
    const float* zs = z + src * 64;
    for (int k = 0; k < 64; ++k) {
        const float hk = zs[k];
        const float* wrow = Wm1 + k * 64;
        #pragma unroll
        for (int j = 0; j < 64; ++j) acc[j] = fmaf(hk, wrow[j], acc[j]);
    }
    const float* zd = z + dst * 64;
    for (int k = 0; k < 64; ++k) {
        const float hk = zd[k];
        const float* wrow = Wm1 + (64 + k) * 64;
        #pragma unroll
        for (int j = 0; j < 64; ++j) acc[j] = fmaf(hk, wrow[j], acc[j]);
    }
    for (int k = 0; k < 64; ++k) {
        const float hk = buf[k][tid];
        const float* wrow = Wm1 + (128 + k) * 64;
        #pragma unroll
        for (int j = 0; j < 64; ++j) acc[j] = fmaf(hk, wrow[j], acc[j]);
    }
    #pragma unroll
    for (int j = 0; j < 64; ++j) buf[j][tid] = fmaxf(acc[j], 0.0f);
    #pragma unroll
    for (int j = 0; j < 64; ++j) acc[j] = bm2[j];
    for (int k = 0; k < 64; ++k) {
        const float hk = buf[k][tid];
        const float* wrow = Wm2 + k * 64;
        #pragma unroll
        for (int j = 0; j < 64; ++j) acc[j] = fmaf(hk, wrow[j], acc[j]);
    }
    float* srow = sums + dst * 64;
    #pragma unroll
    for (int j = 0; j < 64; ++j) atomicAdd(&srow[j], acc[j]);
    atomicAdd(&cnt[dst], 1.0f);
}

__global__ __launch_bounds__(256) void node_kernel_atomic(
    const float* __restrict__ z,
    const float* __restrict__ Wu1, const float* __restrict__ bu1,
    float* __restrict__ out, const float* __restrict__ cnt)
{
    const int node = (blockIdx.x * 256 + threadIdx.x) >> 6;
    const int j = threadIdx.x & 63;
    const int base = node * 64;
    const float inv = 1.0f / fmaxf(cnt[node], 1.0f);
    const float zj = z[base + j];
    const float mj = out[base + j] * inv;
    float a = bu1[j];
    for (int k = 0; k < 64; ++k)
        a = fmaf(__shfl(zj, k, 64), Wu1[k * 64 + j], a);
    for (int k = 0; k < 64; ++k)
        a = fmaf(__shfl(mj, k, 64), Wu1[(64 + k) * 64 + j], a);
    out[base + j] = fmaxf(a, 0.0f);
}

extern "C" void kernel_launch(void* const* d_in, const int* in_sizes, int n_in,
                              void* d_out, int out_size, void* d_ws, size_t ws_size,
                              hipStream_t stream) {
    const float* z    = (const float*)d_in[0];
    const float* cent = (const float*)d_in[1];
    const int*   ei   = (const int*)d_in[2];
    const float* We1  = (const float*)d_in[3];
    const float* be1  = (const float*)d_in[4];
    const float* We2  = (const float*)d_in[5];
    const float* be2  = (const float*)d_in[6];
    const float* Wm1  = (const float*)d_in[7];
    const float* bm1  = (const float*)d_in[8];
    const float* Wm2  = (const float*)d_in[9];
    const float* bm2  = (const float*)d_in[10];
    const float* Wu1  = (const float*)d_in[11];
    const float* bu1  = (const float*)d_in[12];
    float* out = (float*)d_out;

    if (ws_size >= TOTAL_WS) {
        _Float16* m_buf = (_Float16*)d_ws;
        int* order = (int*)((char*)d_ws + ORDER_OFF);
        int* deg   = (int*)((char*)d_ws + DEG_OFF);
        int* off   = (int*)((char*)d_ws + OFF_OFF);
        int* bsum  = (int*)((char*)d_ws + BSUM_OFF);
        _Float16* wt = (_Float16*)((char*)d_ws + WT_OFF);

        hipMemsetAsync(deg, 0, Nn * sizeof(int), stream);
        wprep_kernel<<<84, 256, 0, stream>>>(We1, We2, Wm1, Wm2, wt);
        hist_kernel<<<Ee / 256, 256, 0, stream>>>(ei, deg);
        scan1_kernel<<<SCAN_NBLK, 1024, 0, stream>>>(deg, off, bsum);
        scan2_kernel<<<1, 64, 0, stream>>>(bsum);
        scan3_kernel<<<SCAN_NBLK, 1024, 0, stream>>>(off, bsum);
        fill_kernel<<<Ee / 256, 256, 0, stream>>>(ei, off, order);
        edge_mfma_kernel<<<Ee / 128, 256, 0, stream>>>(z, cent, ei, order, wt,
            be1, be2, bm1, bm2, m_buf);
        node_kernel<<<Nn / 4, 256, 0, stream>>>(z, Wu1, bu1, m_buf, deg, off, out);
    } else {
        float* cnt = (float*)d_ws;
        hipMemsetAsync(out, 0, (size_t)Nn * 64 * sizeof(float), stream);
        hipMemsetAsync(cnt, 0, (size_t)Nn * sizeof(float), stream);
        edge_kernel_atomic<<<Ee / 256, 256, 0, stream>>>(z, cent, ei,
            We1, be1, We2, be2, Wm1, bm1, Wm2, bm2, out, cnt);
        node_kernel_atomic<<<Nn / 4, 256, 0, stream>>>(z, Wu1, bu1, out, cnt);
    }
}

// Round 4
// 415.575 us; speedup vs baseline: 7.5481x; 1.0301x over previous
//
#include <hip/hip_runtime.h>

#define Nn 50000
#define Ee 800000

typedef _Float16 half8 __attribute__((ext_vector_type(8)));
typedef _Float16 half4 __attribute__((ext_vector_type(4)));
typedef float floatx16 __attribute__((ext_vector_type(16)));

// ---- workspace layout (bytes) ----
#define MBUF_BYTES  ((size_t)Ee * 64 * 2)                // 102,400,000  f16 m
#define SD_OFF      MBUF_BYTES                           // int2[Ee] sorted (src,dst)
#define DEG_OFF     (SD_OFF + (size_t)Ee * 8)            // 108,800,000
#define OFF_OFF     (DEG_OFF + (size_t)Nn * 4)
#define BSUM_OFF    (OFF_OFF + (size_t)Nn * 4)
#define WT_OFF      (BSUM_OFF + 256)                     // 16B-aligned
#define WT_HALVES   21504
#define Z16_OFF     (WT_OFF + (size_t)WT_HALVES * 2)     // 16B-aligned
#define C4_OFF      (Z16_OFF + (size_t)Nn * 64 * 2)      // float4[Nn]
#define TOTAL_WS    (C4_OFF + (size_t)Nn * 16)

// wt sub-offsets (halves)
#define WE1T 0
#define WE2T 1024
#define WM1T 5120
#define WM2T 17408

// prep kernel grid partition
#define ZP_NB   1563   // z -> f16   (3.2M halves / (256*8))
#define C4_NB   196    // cent -> float4
#define WT_NB   84     // weights transpose+cvt
#define HI_NB   3125   // histogram
#define PREP_NB (ZP_NB + C4_NB + WT_NB + HI_NB)

// ===========================================================================
// Fused prep: z->f16, cent->float4, weight transpose/cvt, dst histogram.
// All four tasks independent; one launch overlaps the latency-bound pieces.
// ===========================================================================
__global__ __launch_bounds__(256) void prep_kernel(
    const float* __restrict__ z, const float* __restrict__ cent,
    const int* __restrict__ ei,
    const float* __restrict__ We1, const float* __restrict__ We2,
    const float* __restrict__ Wm1, const float* __restrict__ Wm2,
    _Float16* __restrict__ z16, float4* __restrict__ cent4,
    _Float16* __restrict__ wt, int* __restrict__ deg)
{
    const int b = blockIdx.x, tid = threadIdx.x;
    if (b < ZP_NB) {                                   // ---- z -> f16
        const int i8 = (b * 256 + tid) * 8;
        if (i8 < Nn * 64) {
            const float4 a4 = *(const float4*)(z + i8);
            const float4 b4 = *(const float4*)(z + i8 + 4);
            half8 hv;
            hv[0] = (_Float16)a4.x; hv[1] = (_Float16)a4.y;
            hv[2] = (_Float16)a4.z; hv[3] = (_Float16)a4.w;
            hv[4] = (_Float16)b4.x; hv[5] = (_Float16)b4.y;
            hv[6] = (_Float16)b4.z; hv[7] = (_Float16)b4.w;
            *(half8*)(z16 + i8) = hv;
        }
    } else if (b < ZP_NB + C4_NB) {                    // ---- cent -> float4
        const int n = (b - ZP_NB) * 256 + tid;
        if (n < Nn)
            cent4[n] = make_float4(cent[n * 3], cent[n * 3 + 1], cent[n * 3 + 2], 0.0f);
    } else if (b < ZP_NB + C4_NB + WT_NB) {            // ---- weights wt[n][k]=W[k][n]
        const int i = (b - ZP_NB - C4_NB) * 256 + tid;
        float v;
        if (i < 1024) {                      // We1t [64][16], K=3 zero-padded
            const int n = i >> 4, k = i & 15;
            v = (k < 3) ? We1[k * 64 + n] : 0.0f;
        } else if (i < 5120) {               // We2t [64][64]
            const int j = i - 1024, n = j >> 6, k = j & 63;
            v = We2[k * 64 + n];
        } else if (i < 17408) {              // Wm1t [64][192]
            const int j = i - 5120, n = j / 192, k = j - n * 192;
            v = Wm1[k * 64 + n];
        } else {                             // Wm2t [64][64]
            const int j = i - 17408, n = j >> 6, k = j & 63;
            v = Wm2[k * 64 + n];
        }
        wt[i] = (_Float16)v;
    } else {                                           // ---- histogram of dst
        const int e = (b - ZP_NB - C4_NB - WT_NB) * 256 + tid;
        atomicAdd(&deg[ei[Ee + e]], 1);
    }
}

// ===========================================================================
// Hierarchical exclusive scan of deg[Nn] -> off[Nn]
// ===========================================================================
#define SCAN_TILE 4096
#define SCAN_NBLK 13

__global__ __launch_bounds__(1024) void scan1_kernel(const int* __restrict__ deg,
                                                     int* __restrict__ off,
                                                     int* __restrict__ bsum) {
    __shared__ int wsum[16];
    const int tid = threadIdx.x;
    const int lane = tid & 63, wid = tid >> 6;
    const int base = blockIdx.x * SCAN_TILE + tid * 4;

    int v0 = (base + 0 < Nn) ? deg[base + 0] : 0;
    int v1 = (base + 1 < Nn) ? deg[base + 1] : 0;
    int v2 = (base + 2 < Nn) ? deg[base + 2] : 0;
    int v3 = (base + 3 < Nn) ? deg[base + 3] : 0;
    const int tsum = v0 + v1 + v2 + v3;

    int x = tsum;
    for (int s = 1; s < 64; s <<= 1) {
        int y = __shfl_up(x, s, 64);
        if (lane >= s) x += y;
    }
    if (lane == 63) wsum[wid] = x;
    __syncthreads();
    if (wid == 0) {
        int w = (lane < 16) ? wsum[lane] : 0;
        for (int s = 1; s < 16; s <<= 1) {
            int y = __shfl_up(w, s, 64);
            if (lane >= s) w += y;
        }
        if (lane < 16) wsum[lane] = w;
    }
    __syncthreads();
    const int wpre = wid ? wsum[wid - 1] : 0;
    const int tpre = wpre + (x - tsum);
    if (base + 0 < Nn) off[base + 0] = tpre;
    if (base + 1 < Nn) off[base + 1] = tpre + v0;
    if (base + 2 < Nn) off[base + 2] = tpre + v0 + v1;
    if (base + 3 < Nn) off[base + 3] = tpre + v0 + v1 + v2;
    if (tid == 1023) bsum[blockIdx.x] = wsum[15];
}

__global__ __launch_bounds__(64) void scan2_kernel(int* __restrict__ bsum) {
    const int lane = threadIdx.x;
    int v = (lane < SCAN_NBLK) ? bsum[lane] : 0;
    int w = v;
    for (int s = 1; s < 64; s <<= 1) {
        int y = __shfl_up(w, s, 64);
        if (lane >= s) w += y;
    }
    if (lane < SCAN_NBLK) bsum[lane] = w - v;
}

__global__ __launch_bounds__(1024) void scan3_kernel(int* __restrict__ off,
                                                     const int* __restrict__ bsum) {
    const int add = bsum[blockIdx.x];
    const int base = blockIdx.x * SCAN_TILE + threadIdx.x * 4;
    if (base + 0 < Nn) off[base + 0] += add;
    if (base + 1 < Nn) off[base + 1] += add;
    if (base + 2 < Nn) off[base + 2] += add;
    if (base + 3 < Nn) off[base + 3] += add;
}

// off[dst] advanced to end pointer; start recovered via deg.
// Writes packed (src,dst) at the sorted slot -> edge kernel needs no random
// ei gathers at all.
__global__ __launch_bounds__(256) void fill_kernel(const int* __restrict__ ei,
                                                   int* __restrict__ off,
                                                   int2* __restrict__ sd) {
    const int e = blockIdx.x * 256 + threadIdx.x;
    const int s = ei[e];
    const int d = ei[Ee + e];
    const int pos = atomicAdd(&off[d], 1);
    sd[pos] = make_int2(s, d);
}

// ===========================================================================
// Edge kernel (MFMA f16): wave = 32 edges, no barriers, per-wave LDS buffer.
// A-frag (32x32x16): A[m=lane&31][k=(lane>>5)*8+j]
// B-frag:            B[k=(lane>>5)*8+j][n=lane&31]  (rows of wt[n][k])
// C/D:               row=(reg&3)+8*(reg>>2)+4*(lane>>5), col=lane&31
// ===========================================================================
#define HPITCH 200

__device__ __forceinline__ floatx16 mfma16(half8 a, half8 b, floatx16 c) {
    return __builtin_amdgcn_mfma_f32_32x32x16_f16(a, b, c, 0, 0, 0);
}

__global__ __launch_bounds__(256) void edge_mfma_kernel(
    const _Float16* __restrict__ z16, const float4* __restrict__ cent4,
    const int2* __restrict__ sd,
    const _Float16* __restrict__ wt,
    const float* __restrict__ be1, const float* __restrict__ be2,
    const float* __restrict__ bm1, const float* __restrict__ bm2,
    _Float16* __restrict__ m_buf)
{
    __shared__ _Float16 hb[4][32][HPITCH];   // 51.2 KB -> 3 blocks/CU
    const int tid = threadIdx.x;
    const int wid = tid >> 6, lane = tid & 63;
    const int er = lane & 31;        // edge row within wave tile
    const int kh = lane >> 5;        // k-half (0: src row / k 0-7, 1: dst row / k 8-15)
    const int tile = (blockIdx.x * 4 + wid) * 32;

    const int p = tile + er;
    const int2 e2i = sd[p];          // coalesced
    const int row = kh ? e2i.y : e2i.x;

    // ---- z16 gather: one 128B row per lane -> LDS ----
    const half8* __restrict__ zr = (const half8*)(z16 + (size_t)row * 64);
    _Float16* __restrict__ hrow = &hb[wid][er][kh * 64];
    #pragma unroll
    for (int c = 0; c < 8; ++c)
        *(half8*)(hrow + c * 8) = zr[c];

    // ---- centroid delta (src vals in lanes 0-31, dst in 32-63) ----
    const float4 cv = cent4[row];
    const float d0 = __shfl(cv.x, er + 32, 64) - __shfl(cv.x, er, 64);
    const float d1 = __shfl(cv.y, er + 32, 64) - __shfl(cv.y, er, 64);
    const float d2 = __shfl(cv.z, er + 32, 64) - __shfl(cv.z, er, 64);

    const _Float16* __restrict__ we1t = wt + WE1T;
    const _Float16* __restrict__ we2t = wt + WE2T;
    const _Float16* __restrict__ wm1t = wt + WM1T;
    const _Float16* __restrict__ wm2t = wt + WM2T;

    // ---- e1 = relu(delta @ We1 + be1): K=16 (3 real), 2 n-tiles ----
    half8 a1;
    #pragma unroll
    for (int j = 0; j < 8; ++j) a1[j] = (_Float16)0.0f;
    if (kh == 0) { a1[0] = (_Float16)d0; a1[1] = (_Float16)d1; a1[2] = (_Float16)d2; }

    #pragma unroll
    for (int nt = 0; nt < 2; ++nt) {
        const int n = nt * 32 + er;
        const float bias = be1[n];
        floatx16 acc;
        #pragma unroll
        for (int r = 0; r < 16; ++r) acc[r] = bias;
        const half8 b = *(const half8*)(we1t + n * 16 + kh * 8);
        acc = mfma16(a1, b, acc);
        #pragma unroll
        for (int r = 0; r < 16; ++r) {
            const int rrow = (r & 3) + 8 * (r >> 2) + 4 * kh;
            hb[wid][rrow][128 + n] = (_Float16)fmaxf(acc[r], 0.0f);
        }
    }

    // ---- e2 = relu(e1 @ We2 + be2): K=64 ----
    {
        const float bias0 = be2[er], bias1 = be2[32 + er];
        floatx16 acc0, acc1;
        #pragma unroll
        for (int r = 0; r < 16; ++r) { acc0[r] = bias0; acc1[r] = bias1; }
        #pragma unroll
        for (int ks = 0; ks < 4; ++ks) {
            const half8 a = *(const half8*)(&hb[wid][er][128 + ks * 16 + kh * 8]);
            const half8 b0 = *(const half8*)(we2t + er * 64 + ks * 16 + kh * 8);
            const half8 b1 = *(const half8*)(we2t + (32 + er) * 64 + ks * 16 + kh * 8);
            acc0 = mfma16(a, b0, acc0);
            acc1 = mfma16(a, b1, acc1);
        }
        #pragma unroll
        for (int r = 0; r < 16; ++r) {
            const int rrow = (r & 3) + 8 * (r >> 2) + 4 * kh;
            hb[wid][rrow][128 + er]      = (_Float16)fmaxf(acc0[r], 0.0f);
            hb[wid][rrow][128 + 32 + er] = (_Float16)fmaxf(acc1[r], 0.0f);
        }
    }

    // ---- h1 = relu([z_src|z_dst|e2] @ Wm1 + bm1): K=192 ----
    {
        const float bias0 = bm1[er], bias1 = bm1[32 + er];
        floatx16 acc0, acc1;
        #pragma unroll
        for (int r = 0; r < 16; ++r) { acc0[r] = bias0; acc1[r] = bias1; }
        #pragma unroll
        for (int ks = 0; ks < 12; ++ks) {
            const half8 a = *(const half8*)(&hb[wid][er][ks * 16 + kh * 8]);
            const half8 b0 = *(const half8*)(wm1t + er * 192 + ks * 16 + kh * 8);
            const half8 b1 = *(const half8*)(wm1t + (32 + er) * 192 + ks * 16 + kh * 8);
            acc0 = mfma16(a, b0, acc0);
            acc1 = mfma16(a, b1, acc1);
        }
        #pragma unroll
        for (int r = 0; r < 16; ++r) {
            const int rrow = (r & 3) + 8 * (r >> 2) + 4 * kh;
            hb[wid][rrow][er]      = (_Float16)fmaxf(acc0[r], 0.0f);
            hb[wid][rrow][32 + er] = (_Float16)fmaxf(acc1[r], 0.0f);
        }
    }

    // ---- m = h1 @ Wm2 + bm2 -> m_buf (nontemporal: don't thrash L2) ----
    {
        const float bias0 = bm2[er], bias1 = bm2[32 + er];
        floatx16 acc0, acc1;
        #pragma unroll
        for (int r = 0; r < 16; ++r) { acc0[r] = bias0; acc1[r] = bias1; }
        #pragma unroll
        for (int ks = 0; ks < 4; ++ks) {
            const half8 a = *(const half8*)(&hb[wid][er][ks * 16 + kh * 8]);
            const half8 b0 = *(const half8*)(wm2t + er * 64 + ks * 16 + kh * 8);
            const half8 b1 = *(const half8*)(wm2t + (32 + er) * 64 + ks * 16 + kh * 8);
            acc0 = mfma16(a, b0, acc0);
            acc1 = mfma16(a, b1, acc1);
        }
        #pragma unroll
        for (int r = 0; r < 16; ++r) {
            const int rrow = (r & 3) + 8 * (r >> 2) + 4 * kh;
            _Float16* mrow = m_buf + (size_t)(tile + rrow) * 64;
            __builtin_nontemporal_store((_Float16)acc0[r], mrow + er);
            __builtin_nontemporal_store((_Float16)acc1[r], mrow + 32 + er);
        }
    }
}

// ===========================================================================
// Node kernel: wave per node. m_buf read 4 rows/iter (half4 per lane,
// 512B per wave-instruction), butterfly merge, then phi_u via shfl.
// ===========================================================================
__global__ __launch_bounds__(256) void node_kernel(
    const float* __restrict__ z,
    const float* __restrict__ Wu1, const float* __restrict__ bu1,
    const _Float16* __restrict__ m_buf, const int* __restrict__ deg,
    const int* __restrict__ off, float* __restrict__ out)
{
    const int node = (blockIdx.x * 256 + threadIdx.x) >> 6;
    const int lane = threadIdx.x & 63;
    const int g = lane >> 4;          // row offset 0..3
    const int c = lane & 15;          // feature group: features 4c..4c+3
    const int dn = deg[node];
    const int start = off[node] - dn;

    float s0 = 0.f, s1 = 0.f, s2 = 0.f, s3 = 0.f;
    const _Float16* __restrict__ base = m_buf + (size_t)start * 64 + c * 4;
    for (int i = g; i < dn; i += 4) {
        const half4 h = *(const half4*)(base + (size_t)i * 64);
        s0 += (float)h[0]; s1 += (float)h[1]; s2 += (float)h[2]; s3 += (float)h[3];
    }
    // merge the 4 row-groups
    s0 += __shfl_xor(s0, 16, 64); s0 += __shfl_xor(s0, 32, 64);
    s1 += __shfl_xor(s1, 16, 64); s1 += __shfl_xor(s1, 32, 64);
    s2 += __shfl_xor(s2, 16, 64); s2 += __shfl_xor(s2, 32, 64);
    s3 += __shfl_xor(s3, 16, 64); s3 += __shfl_xor(s3, 32, 64);

    // redistribute: feature j=lane lives at lane (j>>2), element (j&3)
    const int cg = lane >> 2, el = lane & 3;
    const float m0 = __shfl(s0, cg, 64);
    const float m1 = __shfl(s1, cg, 64);
    const float m2 = __shfl(s2, cg, 64);
    const float m3 = __shfl(s3, cg, 64);
    const float msum = (el == 0) ? m0 : (el == 1) ? m1 : (el == 2) ? m2 : m3;
    const float M = msum * (1.0f / fmaxf((float)dn, 1.0f));

    const float zj = z[node * 64 + lane];
    float a = bu1[lane];
    for (int k = 0; k < 64; ++k)
        a = fmaf(__shfl(zj, k, 64), Wu1[k * 64 + lane], a);
    for (int k = 0; k < 64; ++k)
        a = fmaf(__shfl(M, k, 64), Wu1[(64 + k) * 64 + lane], a);

    out[node * 64 + lane] = fmaxf(a, 0.0f);
}

// ===========================================================================
// Fallback (atomic, fp32) — only if ws_size too small. Known-correct (R1).
// ===========================================================================
__global__ __launch_bounds__(256) void edge_kernel_atomic(
    const float* __restrict__ z, const float* __restrict__ cent,
    const int* __restrict__ ei,
    const float* __restrict__ We1, const float* __restrict__ be1,
    const float* __restrict__ We2, const float* __restrict__ be2,
    const float* __restrict__ Wm1, const float* __restrict__ bm1,
    const float* __restrict__ Wm2, const float* __restrict__ bm2,
    float* __restrict__ sums, float* __restrict__ cnt)
{
    __shared__ float buf[64][256];
    const int tid = threadIdx.x;
    const int e = blockIdx.x * 256 + tid;
    const int src = ei[e];
    const int dst = ei[Ee + e];
    const float d0 = cent[dst * 3 + 0] - cent[src * 3 + 0];
    const float d1 = cent[dst * 3 + 1] - cent[src * 3 + 1];
    const float d2 = cent[dst * 3 + 2] - cent[src * 3 + 2];
    for (int j = 0; j < 64; ++j) {
        float v = fmaf(d0, We1[j], fmaf(d1, We1[64 + j], fmaf(d2, We1[128 + j], be1[j])));
        buf[j][tid] = fmaxf(v, 0.0f);
    }
    float acc[64];
    #pragma unroll
    for (int j = 0; j < 64; ++j) acc[j] = be2[j];
    for (int k = 0; k < 64; ++k) {
        const float ek = buf[k][tid];
        const float* wrow = We2 + k * 64;
        #pragma unroll
        for (int j = 0; j < 64; ++j) acc[j] = fmaf(ek, wrow[j], acc[j]);
    }
    #pragma unroll
    for (int j = 0; j < 64; ++j) buf[j][tid] = fmaxf(acc[j], 0.0f);
    #pragma unroll
    for (int j = 0; j < 64; ++j) acc[j] = bm1[j];
    const float* zs = z + src * 64;
    for (int k = 0; k < 64; ++k) {
        const float hk = zs[k];
        const float* wrow = Wm1 + k * 64;
        #pragma unroll
        for (int j = 0; j < 64; ++j) acc[j] = fmaf(hk, wrow[j], acc[j]);
    }
    const float* zd = z + dst * 64;
    for (int k = 0; k < 64; ++k) {
        const float hk = zd[k];
        const float* wrow = Wm1 + (64 + k) * 64;
        #pragma unroll
        for (int j = 0; j < 64; ++j) acc[j] = fmaf(hk, wrow[j], acc[j]);
    }
    for (int k = 0; k < 64; ++k) {
        const float hk = buf[k][tid];
        const float* wrow = Wm1 + (128 + k) * 64;
        #pragma unroll
        for (int j = 0; j < 64; ++j) acc[j] = fmaf(hk, wrow[j], acc[j]);
    }
    #pragma unroll
    for (int j = 0; j < 64; ++j) buf[j][tid] = fmaxf(acc[j], 0.0f);
    #pragma unroll
    for (int j = 0; j < 64; ++j) acc[j] = bm2[j];
    for (int k = 0; k < 64; ++k) {
        const float hk = buf[k][tid];
        const float* wrow = Wm2 + k * 64;
        #pragma unroll
        for (int j = 0; j < 64; ++j) acc[j] = fmaf(hk, wrow[j], acc[j]);
    }
    float* srow = sums + dst * 64;
    #pragma unroll
    for (int j = 0; j < 64; ++j) atomicAdd(&srow[j], acc[j]);
    atomicAdd(&cnt[dst], 1.0f);
}

__global__ __launch_bounds__(256) void node_kernel_atomic(
    const float* __restrict__ z,
    const float* __restrict__ Wu1, const float* __restrict__ bu1,
    float* __restrict__ out, const float* __restrict__ cnt)
{
    const int node = (blockIdx.x * 256 + threadIdx.x) >> 6;
    const int j = threadIdx.x & 63;
    const int base = node * 64;
    const float inv = 1.0f / fmaxf(cnt[node], 1.0f);
    const float zj = z[base + j];
    const float mj = out[base + j] * inv;
    float a = bu1[j];
    for (int k = 0; k < 64; ++k)
        a = fmaf(__shfl(zj, k, 64), Wu1[k * 64 + j], a);
    for (int k = 0; k < 64; ++k)
        a = fmaf(__shfl(mj, k, 64), Wu1[(64 + k) * 64 + j], a);
    out[base + j] = fmaxf(a, 0.0f);
}

extern "C" void kernel_launch(void* const* d_in, const int* in_sizes, int n_in,
                              void* d_out, int out_size, void* d_ws, size_t ws_size,
                              hipStream_t stream) {
    const float* z    = (const float*)d_in[0];
    const float* cent = (const float*)d_in[1];
    const int*   ei   = (const int*)d_in[2];
    const float* We1  = (const float*)d_in[3];
    const float* be1  = (const float*)d_in[4];
    const float* We2  = (const float*)d_in[5];
    const float* be2  = (const float*)d_in[6];
    const float* Wm1  = (const float*)d_in[7];
    const float* bm1  = (const float*)d_in[8];
    const float* Wm2  = (const float*)d_in[9];
    const float* bm2  = (const float*)d_in[10];
    const float* Wu1  = (const float*)d_in[11];
    const float* bu1  = (const float*)d_in[12];
    float* out = (float*)d_out;

    if (ws_size >= TOTAL_WS) {
        _Float16* m_buf = (_Float16*)d_ws;
        int2* sd   = (int2*)((char*)d_ws + SD_OFF);
        int* deg   = (int*)((char*)d_ws + DEG_OFF);
        int* off   = (int*)((char*)d_ws + OFF_OFF);
        int* bsum  = (int*)((char*)d_ws + BSUM_OFF);
        _Float16* wt  = (_Float16*)((char*)d_ws + WT_OFF);
        _Float16* z16 = (_Float16*)((char*)d_ws + Z16_OFF);
        float4* cent4 = (float4*)((char*)d_ws + C4_OFF);

        hipMemsetAsync(deg, 0, Nn * sizeof(int), stream);
        prep_kernel<<<PREP_NB, 256, 0, stream>>>(z, cent, ei, We1, We2, Wm1, Wm2,
                                                 z16, cent4, wt, deg);
        scan1_kernel<<<SCAN_NBLK, 1024, 0, stream>>>(deg, off, bsum);
        scan2_kernel<<<1, 64, 0, stream>>>(bsum);
        scan3_kernel<<<SCAN_NBLK, 1024, 0, stream>>>(off, bsum);
        fill_kernel<<<Ee / 256, 256, 0, stream>>>(ei, off, sd);
        edge_mfma_kernel<<<Ee / 128, 256, 0, stream>>>(z16, cent4, sd, wt,
            be1, be2, bm1, bm2, m_buf);
        node_kernel<<<Nn / 4, 256, 0, stream>>>(z, Wu1, bu1, m_buf, deg, off, out);
    } else {
        float* cnt = (float*)d_ws;
        hipMemsetAsync(out, 0, (size_t)Nn * 64 * sizeof(float), stream);
        hipMemsetAsync(cnt, 0, (size_t)Nn * sizeof(float), stream);
        edge_kernel_atomic<<<Ee / 256, 256, 0, stream>>>(z, cent, ei,
            We1, be1, We2, be2, Wm1, bm1, Wm2, bm2, out, cnt);
        node_kernel_atomic<<<Nn / 4, 256, 0, stream>>>(z, Wu1, bu1, out, cnt);
    }
}

// Round 5
// 399.441 us; speedup vs baseline: 7.8529x; 1.0404x over previous
//
#include <hip/hip_runtime.h>

#define Nn 50000
#define Ee 800000

typedef _Float16 half8 __attribute__((ext_vector_type(8)));
typedef float floatx16 __attribute__((ext_vector_type(16)));

// ---- workspace layout (bytes) ----
#define SD_OFF      0                                    // int2[Ee] sorted (src,dst)
#define DEG_OFF     ((size_t)Ee * 8)                     // 6,400,000
#define OFF_OFF     (DEG_OFF + (size_t)Nn * 4)
#define BSUM_OFF    (OFF_OFF + (size_t)Nn * 4)
#define WT_OFF      (BSUM_OFF + 256)                     // 16B-aligned
#define WT_HALVES   21504
#define Z16_OFF     (WT_OFF + (size_t)WT_HALVES * 2)
#define C4_OFF      (Z16_OFF + (size_t)Nn * 64 * 2)
#define TOTAL_WS    (C4_OFF + (size_t)Nn * 16)           // ~14 MB

// wt sub-offsets (halves)
#define WE1T 0
#define WE2T 1024
#define WM1T 5120
#define WM2T 17408

// prep kernel grid partition
#define ZP_NB   1563
#define C4_NB   196
#define WT_NB   84
#define HI_NB   3125
#define PREP_NB (ZP_NB + C4_NB + WT_NB + HI_NB)

// ===========================================================================
// Fused prep: z->f16, cent->float4, weight transpose/cvt, dst histogram.
// ===========================================================================
__global__ __launch_bounds__(256) void prep_kernel(
    const float* __restrict__ z, const float* __restrict__ cent,
    const int* __restrict__ ei,
    const float* __restrict__ We1, const float* __restrict__ We2,
    const float* __restrict__ Wm1, const float* __restrict__ Wm2,
    _Float16* __restrict__ z16, float4* __restrict__ cent4,
    _Float16* __restrict__ wt, int* __restrict__ deg)
{
    const int b = blockIdx.x, tid = threadIdx.x;
    if (b < ZP_NB) {                                   // ---- z -> f16
        const int i8 = (b * 256 + tid) * 8;
        if (i8 < Nn * 64) {
            const float4 a4 = *(const float4*)(z + i8);
            const float4 b4 = *(const float4*)(z + i8 + 4);
            half8 hv;
            hv[0] = (_Float16)a4.x; hv[1] = (_Float16)a4.y;
            hv[2] = (_Float16)a4.z; hv[3] = (_Float16)a4.w;
            hv[4] = (_Float16)b4.x; hv[5] = (_Float16)b4.y;
            hv[6] = (_Float16)b4.z; hv[7] = (_Float16)b4.w;
            *(half8*)(z16 + i8) = hv;
        }
    } else if (b < ZP_NB + C4_NB) {                    // ---- cent -> float4
        const int n = (b - ZP_NB) * 256 + tid;
        if (n < Nn)
            cent4[n] = make_float4(cent[n * 3], cent[n * 3 + 1], cent[n * 3 + 2], 0.0f);
    } else if (b < ZP_NB + C4_NB + WT_NB) {            // ---- weights wt[n][k]=W[k][n]
        const int i = (b - ZP_NB - C4_NB) * 256 + tid;
        float v;
        if (i < 1024) {                      // We1t [64][16], K=3 zero-padded
            const int n = i >> 4, k = i & 15;
            v = (k < 3) ? We1[k * 64 + n] : 0.0f;
        } else if (i < 5120) {               // We2t [64][64]
            const int j = i - 1024, n = j >> 6, k = j & 63;
            v = We2[k * 64 + n];
        } else if (i < 17408) {              // Wm1t [64][192]
            const int j = i - 5120, n = j / 192, k = j - n * 192;
            v = Wm1[k * 64 + n];
        } else {                             // Wm2t [64][64]
            const int j = i - 17408, n = j >> 6, k = j & 63;
            v = Wm2[k * 64 + n];
        }
        wt[i] = (_Float16)v;
    } else {                                           // ---- histogram of dst
        const int e = (b - ZP_NB - C4_NB - WT_NB) * 256 + tid;
        atomicAdd(&deg[ei[Ee + e]], 1);
    }
}

// ===========================================================================
// Hierarchical exclusive scan of deg[Nn] -> off[Nn]
// ===========================================================================
#define SCAN_TILE 4096
#define SCAN_NBLK 13

__global__ __launch_bounds__(1024) void scan1_kernel(const int* __restrict__ deg,
                                                     int* __restrict__ off,
                                                     int* __restrict__ bsum) {
    __shared__ int wsum[16];
    const int tid = threadIdx.x;
    const int lane = tid & 63, wid = tid >> 6;
    const int base = blockIdx.x * SCAN_TILE + tid * 4;

    int v0 = (base + 0 < Nn) ? deg[base + 0] : 0;
    int v1 = (base + 1 < Nn) ? deg[base + 1] : 0;
    int v2 = (base + 2 < Nn) ? deg[base + 2] : 0;
    int v3 = (base + 3 < Nn) ? deg[base + 3] : 0;
    const int tsum = v0 + v1 + v2 + v3;

    int x = tsum;
    for (int s = 1; s < 64; s <<= 1) {
        int y = __shfl_up(x, s, 64);
        if (lane >= s) x += y;
    }
    if (lane == 63) wsum[wid] = x;
    __syncthreads();
    if (wid == 0) {
        int w = (lane < 16) ? wsum[lane] : 0;
        for (int s = 1; s < 16; s <<= 1) {
            int y = __shfl_up(w, s, 64);
            if (lane >= s) w += y;
        }
        if (lane < 16) wsum[lane] = w;
    }
    __syncthreads();
    const int wpre = wid ? wsum[wid - 1] : 0;
    const int tpre = wpre + (x - tsum);
    if (base + 0 < Nn) off[base + 0] = tpre;
    if (base + 1 < Nn) off[base + 1] = tpre + v0;
    if (base + 2 < Nn) off[base + 2] = tpre + v0 + v1;
    if (base + 3 < Nn) off[base + 3] = tpre + v0 + v1 + v2;
    if (tid == 1023) bsum[blockIdx.x] = wsum[15];
}

__global__ __launch_bounds__(64) void scan2_kernel(int* __restrict__ bsum) {
    const int lane = threadIdx.x;
    int v = (lane < SCAN_NBLK) ? bsum[lane] : 0;
    int w = v;
    for (int s = 1; s < 64; s <<= 1) {
        int y = __shfl_up(w, s, 64);
        if (lane >= s) w += y;
    }
    if (lane < SCAN_NBLK) bsum[lane] = w - v;
}

__global__ __launch_bounds__(1024) void scan3_kernel(int* __restrict__ off,
                                                     const int* __restrict__ bsum) {
    const int add = bsum[blockIdx.x];
    const int base = blockIdx.x * SCAN_TILE + threadIdx.x * 4;
    if (base + 0 < Nn) off[base + 0] += add;
    if (base + 1 < Nn) off[base + 1] += add;
    if (base + 2 < Nn) off[base + 2] += add;
    if (base + 3 < Nn) off[base + 3] += add;
}

// off[dst] advanced to end pointer (not needed afterwards).
__global__ __launch_bounds__(256) void fill_kernel(const int* __restrict__ ei,
                                                   int* __restrict__ off,
                                                   int2* __restrict__ sd) {
    const int e = blockIdx.x * 256 + threadIdx.x;
    const int s = ei[e];
    const int d = ei[Ee + e];
    const int pos = atomicAdd(&off[d], 1);
    sd[pos] = make_int2(s, d);
}

// ===========================================================================
// Edge kernel (MFMA f16): wave = 32 sorted edges, no barriers.
// A-frag (32x32x16): A[m=lane&31][k=(lane>>5)*8+j]
// B-frag:            B[k=(lane>>5)*8+j][n=lane&31]  (rows of wt[n][k])
// C/D:               row=(reg&3)+8*(reg>>2)+4*(lane>>5), col=lane&31
// Final m stays in registers; segmented (by dst) reduction over edge-rows via
// predicated adds + shfl_xor(32), then ONE coalesced 64-lane atomicAdd per
// segment into sums[dst][0..63]. No m_buf materialization.
// ===========================================================================
#define HPITCH 200

__device__ __forceinline__ floatx16 mfma16(half8 a, half8 b, floatx16 c) {
    return __builtin_amdgcn_mfma_f32_32x32x16_f16(a, b, c, 0, 0, 0);
}

__global__ __launch_bounds__(256) void edge_mfma_kernel(
    const _Float16* __restrict__ z16, const float4* __restrict__ cent4,
    const int2* __restrict__ sd,
    const _Float16* __restrict__ wt,
    const float* __restrict__ be1, const float* __restrict__ be2,
    const float* __restrict__ bm1, const float* __restrict__ bm2,
    float* __restrict__ sums)
{
    __shared__ _Float16 hb[4][32][HPITCH];   // 51.2 KB -> 3 blocks/CU
    const int tid = threadIdx.x;
    const int wid = tid >> 6, lane = tid & 63;
    const int er = lane & 31;        // edge row within wave tile
    const int kh = lane >> 5;        // 0: src row / k 0-7, 1: dst row / k 8-15
    const int tile = (blockIdx.x * 4 + wid) * 32;

    const int p = tile + er;
    const int2 e2i = sd[p];          // coalesced; every lane has (src,dst) of edge er
    const int row = kh ? e2i.y : e2i.x;

    // ---- z16 gather: one 128B row per lane -> LDS ----
    const half8* __restrict__ zr = (const half8*)(z16 + (size_t)row * 64);
    _Float16* __restrict__ hrow = &hb[wid][er][kh * 64];
    #pragma unroll
    for (int c = 0; c < 8; ++c)
        *(half8*)(hrow + c * 8) = zr[c];

    // ---- centroid delta (src vals in lanes 0-31, dst in 32-63) ----
    const float4 cv = cent4[row];
    const float d0 = __shfl(cv.x, er + 32, 64) - __shfl(cv.x, er, 64);
    const float d1 = __shfl(cv.y, er + 32, 64) - __shfl(cv.y, er, 64);
    const float d2 = __shfl(cv.z, er + 32, 64) - __shfl(cv.z, er, 64);

    const _Float16* __restrict__ we1t = wt + WE1T;
    const _Float16* __restrict__ we2t = wt + WE2T;
    const _Float16* __restrict__ wm1t = wt + WM1T;
    const _Float16* __restrict__ wm2t = wt + WM2T;

    // ---- e1 = relu(delta @ We1 + be1): K=16 (3 real), 2 n-tiles ----
    half8 a1;
    #pragma unroll
    for (int j = 0; j < 8; ++j) a1[j] = (_Float16)0.0f;
    if (kh == 0) { a1[0] = (_Float16)d0; a1[1] = (_Float16)d1; a1[2] = (_Float16)d2; }

    #pragma unroll
    for (int nt = 0; nt < 2; ++nt) {
        const int n = nt * 32 + er;
        const float bias = be1[n];
        floatx16 acc;
        #pragma unroll
        for (int r = 0; r < 16; ++r) acc[r] = bias;
        const half8 b = *(const half8*)(we1t + n * 16 + kh * 8);
        acc = mfma16(a1, b, acc);
        #pragma unroll
        for (int r = 0; r < 16; ++r) {
            const int rrow = (r & 3) + 8 * (r >> 2) + 4 * kh;
            hb[wid][rrow][128 + n] = (_Float16)fmaxf(acc[r], 0.0f);
        }
    }

    // ---- e2 = relu(e1 @ We2 + be2): K=64 ----
    {
        const float bias0 = be2[er], bias1 = be2[32 + er];
        floatx16 acc0, acc1;
        #pragma unroll
        for (int r = 0; r < 16; ++r) { acc0[r] = bias0; acc1[r] = bias1; }
        #pragma unroll
        for (int ks = 0; ks < 4; ++ks) {
            const half8 a = *(const half8*)(&hb[wid][er][128 + ks * 16 + kh * 8]);
            const half8 b0 = *(const half8*)(we2t + er * 64 + ks * 16 + kh * 8);
            const half8 b1 = *(const half8*)(we2t + (32 + er) * 64 + ks * 16 + kh * 8);
            acc0 = mfma16(a, b0, acc0);
            acc1 = mfma16(a, b1, acc1);
        }
        #pragma unroll
        for (int r = 0; r < 16; ++r) {
            const int rrow = (r & 3) + 8 * (r >> 2) + 4 * kh;
            hb[wid][rrow][128 + er]      = (_Float16)fmaxf(acc0[r], 0.0f);
            hb[wid][rrow][128 + 32 + er] = (_Float16)fmaxf(acc1[r], 0.0f);
        }
    }

    // ---- h1 = relu([z_src|z_dst|e2] @ Wm1 + bm1): K=192 ----
    {
        const float bias0 = bm1[er], bias1 = bm1[32 + er];
        floatx16 acc0, acc1;
        #pragma unroll
        for (int r = 0; r < 16; ++r) { acc0[r] = bias0; acc1[r] = bias1; }
        #pragma unroll
        for (int ks = 0; ks < 12; ++ks) {
            const half8 a = *(const half8*)(&hb[wid][er][ks * 16 + kh * 8]);
            const half8 b0 = *(const half8*)(wm1t + er * 192 + ks * 16 + kh * 8);
            const half8 b1 = *(const half8*)(wm1t + (32 + er) * 192 + ks * 16 + kh * 8);
            acc0 = mfma16(a, b0, acc0);
            acc1 = mfma16(a, b1, acc1);
        }
        #pragma unroll
        for (int r = 0; r < 16; ++r) {
            const int rrow = (r & 3) + 8 * (r >> 2) + 4 * kh;
            hb[wid][rrow][er]      = (_Float16)fmaxf(acc0[r], 0.0f);
            hb[wid][rrow][32 + er] = (_Float16)fmaxf(acc1[r], 0.0f);
        }
    }

    // ---- m = h1 @ Wm2 + bm2 (stays in registers) ----
    floatx16 acc0, acc1;
    {
        const float bias0 = bm2[er], bias1 = bm2[32 + er];
        #pragma unroll
        for (int r = 0; r < 16; ++r) { acc0[r] = bias0; acc1[r] = bias1; }
        #pragma unroll
        for (int ks = 0; ks < 4; ++ks) {
            const half8 a = *(const half8*)(&hb[wid][er][ks * 16 + kh * 8]);
            const half8 b0 = *(const half8*)(wm2t + er * 64 + ks * 16 + kh * 8);
            const half8 b1 = *(const half8*)(wm2t + (32 + er) * 64 + ks * 16 + kh * 8);
            acc0 = mfma16(a, b0, acc0);
            acc1 = mfma16(a, b1, acc1);
        }
    }

    // ---- segmented (by dst) reduction over edge-rows + coalesced atomics ----
    // boundary mask: edge er starts a new segment
    const int dprev = __shfl(e2i.y, (er + 31) & 31, 64);
    const bool boundary = (er == 0) || (e2i.y != dprev);
    unsigned int m32 = (unsigned int)__ballot(boundary);   // bits 0..31 (mirrored)

    while (m32) {
        const int a = __builtin_ctz(m32);
        m32 &= m32 - 1;
        const int b = m32 ? __builtin_ctz(m32) : 32;
        // per-lane partial sums over rows rrow in [a,b)
        float p0 = 0.0f, p1 = 0.0f;
        #pragma unroll
        for (int r = 0; r < 16; ++r) {
            const int rrow = (r & 3) + 8 * (r >> 2) + 4 * kh;
            if (rrow >= a && rrow < b) { p0 += acc0[r]; p1 += acc1[r]; }
        }
        // merge complementary row-halves (lane l <-> l+32 hold same features)
        p0 += __shfl_xor(p0, 32, 64);
        p1 += __shfl_xor(p1, 32, 64);
        const float val = kh ? p1 : p0;          // lane l -> feature l
        const int dseg = __shfl(e2i.y, a, 64);   // dst of this segment
        atomicAdd(&sums[(size_t)dseg * 64 + lane], val);
    }
}

// ===========================================================================
// Node kernel: wave per node, lane = feature. sums row (in d_out) -> mean ->
// phi_u via shfl broadcast -> overwrite d_out in place.
// ===========================================================================
__global__ __launch_bounds__(256) void node_kernel(
    const float* __restrict__ z,
    const float* __restrict__ Wu1, const float* __restrict__ bu1,
    const int* __restrict__ deg, float* __restrict__ out)
{
    const int node = (blockIdx.x * 256 + threadIdx.x) >> 6;
    const int lane = threadIdx.x & 63;
    const int dn = deg[node];

    const float M = out[node * 64 + lane] * (1.0f / fmaxf((float)dn, 1.0f));
    const float zj = z[node * 64 + lane];

    float a = bu1[lane];
    for (int k = 0; k < 64; ++k)
        a = fmaf(__shfl(zj, k, 64), Wu1[k * 64 + lane], a);
    for (int k = 0; k < 64; ++k)
        a = fmaf(__shfl(M, k, 64), Wu1[(64 + k) * 64 + lane], a);

    out[node * 64 + lane] = fmaxf(a, 0.0f);   // wave only touches its own row
}

// ===========================================================================
// Fallback (atomic, fp32) — only if ws_size too small. Known-correct (R1).
// ===========================================================================
__global__ __launch_bounds__(256) void edge_kernel_atomic(
    const float* __restrict__ z, const float* __restrict__ cent,
    const int* __restrict__ ei,
    const float* __restrict__ We1, const float* __restrict__ be1,
    const float* __restrict__ We2, const float* __restrict__ be2,
    const float* __restrict__ Wm1, const float* __restrict__ bm1,
    const float* __restrict__ Wm2, const float* __restrict__ bm2,
    float* __restrict__ sums, float* __restrict__ cnt)
{
    __shared__ float buf[64][256];
    const int tid = threadIdx.x;
    const int e = blockIdx.x * 256 + tid;
    const int src = ei[e];
    const int dst = ei[Ee + e];
    const float d0 = cent[dst * 3 + 0] - cent[src * 3 + 0];
    const float d1 = cent[dst * 3 + 1] - cent[src * 3 + 1];
    const float d2 = cent[dst * 3 + 2] - cent[src * 3 + 2];
    for (int j = 0; j < 64; ++j) {
        float v = fmaf(d0, We1[j], fmaf(d1, We1[64 + j], fmaf(d2, We1[128 + j], be1[j])));
        buf[j][tid] = fmaxf(v, 0.0f);
    }
    float acc[64];
    #pragma unroll
    for (int j = 0; j < 64; ++j) acc[j] = be2[j];
    for (int k = 0; k < 64; ++k) {
        const float ek = buf[k][tid];
        const float* wrow = We2 + k * 64;
        #pragma unroll
        for (int j = 0; j < 64; ++j) acc[j] = fmaf(ek, wrow[j], acc[j]);
    }
    #pragma unroll
    for (int j = 0; j < 64; ++j) buf[j][tid] = fmaxf(acc[j], 0.0f);
    #pragma unroll
    for (int j = 0; j < 64; ++j) acc[j] = bm1[j];
    const float* zs = z + src * 64;
    for (int k = 0; k < 64; ++k) {
        const float hk = zs[k];
        const float* wrow = Wm1 + k * 64;
        #pragma unroll
        for (int j = 0; j < 64; ++j) acc[j] = fmaf(hk, wrow[j], acc[j]);
    }
    const float* zd = z + dst * 64;
    for (int k = 0; k < 64; ++k) {
        const float hk = zd[k];
        const float* wrow = Wm1 + (64 + k) * 64;
        #pragma unroll
        for (int j = 0; j < 64; ++j) acc[j] = fmaf(hk, wrow[j], acc[j]);
    }
    for (int k = 0; k < 64; ++k) {
        const float hk = buf[k][tid];
        const float* wrow = Wm1 + (128 + k) * 64;
        #pragma unroll
        for (int j = 0; j < 64; ++j) acc[j] = fmaf(hk, wrow[j], acc[j]);
    }
    #pragma unroll
    for (int j = 0; j < 64; ++j) buf[j][tid] = fmaxf(acc[j], 0.0f);
    #pragma unroll
    for (int j = 0; j < 64; ++j) acc[j] = bm2[j];
    for (int k = 0; k < 64; ++k) {
        const float hk = buf[k][tid];
        const float* wrow = Wm2 + k * 64;
        #pragma unroll
        for (int j = 0; j < 64; ++j) acc[j] = fmaf(hk, wrow[j], acc[j]);
    }
    float* srow = sums + dst * 64;
    #pragma unroll
    for (int j = 0; j < 64; ++j) atomicAdd(&srow[j], acc[j]);
    atomicAdd(&cnt[dst], 1.0f);
}

__global__ __launch_bounds__(256) void node_kernel_atomic(
    const float* __restrict__ z,
    const float* __restrict__ Wu1, const float* __restrict__ bu1,
    float* __restrict__ out, const float* __restrict__ cnt)
{
    const int node = (blockIdx.x * 256 + threadIdx.x) >> 6;
    const int j = threadIdx.x & 63;
    const int base = node * 64;
    const float inv = 1.0f / fmaxf(cnt[node], 1.0f);
    const float zj = z[base + j];
    const float mj = out[base + j] * inv;
    float a = bu1[j];
    for (int k = 0; k < 64; ++k)
        a = fmaf(__shfl(zj, k, 64), Wu1[k * 64 + j], a);
    for (int k = 0; k < 64; ++k)
        a = fmaf(__shfl(mj, k, 64), Wu1[(64 + k) * 64 + j], a);
    out[base + j] = fmaxf(a, 0.0f);
}

extern "C" void kernel_launch(void* const* d_in, const int* in_sizes, int n_in,
                              void* d_out, int out_size, void* d_ws, size_t ws_size,
                              hipStream_t stream) {
    const float* z    = (const float*)d_in[0];
    const float* cent = (const float*)d_in[1];
    const int*   ei   = (const int*)d_in[2];
    const float* We1  = (const float*)d_in[3];
    const float* be1  = (const float*)d_in[4];
    const float* We2  = (const float*)d_in[5];
    const float* be2  = (const float*)d_in[6];
    const float* Wm1  = (const float*)d_in[7];
    const float* bm1  = (const float*)d_in[8];
    const float* Wm2  = (const float*)d_in[9];
    const float* bm2  = (const float*)d_in[10];
    const float* Wu1  = (const float*)d_in[11];
    const float* bu1  = (const float*)d_in[12];
    float* out = (float*)d_out;

    if (ws_size >= TOTAL_WS) {
        int2* sd   = (int2*)((char*)d_ws + SD_OFF);
        int* deg   = (int*)((char*)d_ws + DEG_OFF);
        int* off   = (int*)((char*)d_ws + OFF_OFF);
        int* bsum  = (int*)((char*)d_ws + BSUM_OFF);
        _Float16* wt  = (_Float16*)((char*)d_ws + WT_OFF);
        _Float16* z16 = (_Float16*)((char*)d_ws + Z16_OFF);
        float4* cent4 = (float4*)((char*)d_ws + C4_OFF);

        hipMemsetAsync(deg, 0, Nn * sizeof(int), stream);
        hipMemsetAsync(out, 0, (size_t)Nn * 64 * sizeof(float), stream);
        prep_kernel<<<PREP_NB, 256, 0, stream>>>(z, cent, ei, We1, We2, Wm1, Wm2,
                                                 z16, cent4, wt, deg);
        scan1_kernel<<<SCAN_NBLK, 1024, 0, stream>>>(deg, off, bsum);
        scan2_kernel<<<1, 64, 0, stream>>>(bsum);
        scan3_kernel<<<SCAN_NBLK, 1024, 0, stream>>>(off, bsum);
        fill_kernel<<<Ee / 256, 256, 0, stream>>>(ei, off, sd);
        edge_mfma_kernel<<<Ee / 128, 256, 0, stream>>>(z16, cent4, sd, wt,
            be1, be2, bm1, bm2, out);
        node_kernel<<<Nn / 4, 256, 0, stream>>>(z, Wu1, bu1, deg, out);
    } else {
        float* cnt = (float*)d_ws;
        hipMemsetAsync(out, 0, (size_t)Nn * 64 * sizeof(float), stream);
        hipMemsetAsync(cnt, 0, (size_t)Nn * sizeof(float), stream);
        edge_kernel_atomic<<<Ee / 256, 256, 0, stream>>>(z, cent, ei,
            We1, be1, We2, be2, Wm1, bm1, Wm2, bm2, out, cnt);
        node_kernel_atomic<<<Nn / 4, 256, 0, stream>>>(z, Wu1, bu1, out, cnt);
    }
}